// Round 1
// baseline (4221.457 us; speedup 1.0000x reference)
//
#include <hip/hip_runtime.h>
#include <hip/hip_bf16.h>

// LSTM: B=16384, T=200, IN=9, H=64, OUT=3, 2 layers + linear head.
// Strategy (round 1, fp32 correctness baseline):
//   grid 256 blocks x 1024 threads. lane = batch (64 batches/block),
//   wave w (0..15) owns hidden cells j = 4w..4w+3.
//   h1/h2 shared via LDS [k][lane]; c1/c2 stay in registers.
//   Weights repacked (prep kernel -> d_ws) to [k][wave][16] so each wave
//   reads one contiguous 64B chunk per k (wave-uniform -> scalar loads).

#define B_TOT   16384
#define T_STEPS 200
#define IN_DIM  9
#define HDIM    64

// ws layout (floats)
#define OFF_IH1  0        // [9][16][16]    = 2304
#define OFF_HH1  2304     // [64][16][16]   = 16384
#define OFF_IH2  18688    // [64][16][16]
#define OFF_HH2  35072    // [64][16][16]
#define OFF_B1   51456    // [16][16]
#define OFF_B2   51712    // [16][16]
#define WS_FLOATS 51968

typedef float v16f __attribute__((ext_vector_type(16)));

__device__ __forceinline__ float fast_sig(float x) {
    // 1/(1+e^-x); e^-x overflow -> inf -> rcp -> 0 (correct saturation)
    return __builtin_amdgcn_rcpf(1.0f + __expf(-x));
}
__device__ __forceinline__ float fast_tanh(float x) {
    // 1 - 2/(1+e^{2x}); saturates correctly at +/-1
    return 1.0f - 2.0f * __builtin_amdgcn_rcpf(1.0f + __expf(2.0f * x));
}

// ---------------- prep: repack weights ----------------
__global__ void pack_kernel(const float* __restrict__ Wih1, const float* __restrict__ Whh1,
                            const float* __restrict__ bih1, const float* __restrict__ bhh1,
                            const float* __restrict__ Wih2, const float* __restrict__ Whh2,
                            const float* __restrict__ bih2, const float* __restrict__ bhh2,
                            float* __restrict__ ws) {
    int e = blockIdx.x * 256 + threadIdx.x;
    if (e >= WS_FLOATS) return;
    if (e < OFF_HH1) {                       // pk_ih1
        int r = e;            int k = r >> 8, w = (r >> 4) & 15, q = r & 15;
        int row = (q >> 2) * 64 + w * 4 + (q & 3);
        ws[e] = Wih1[row * IN_DIM + k];
    } else if (e < OFF_IH2) {                // pk_hh1
        int r = e - OFF_HH1;  int k = r >> 8, w = (r >> 4) & 15, q = r & 15;
        int row = (q >> 2) * 64 + w * 4 + (q & 3);
        ws[e] = Whh1[row * HDIM + k];
    } else if (e < OFF_HH2) {                // pk_ih2
        int r = e - OFF_IH2;  int k = r >> 8, w = (r >> 4) & 15, q = r & 15;
        int row = (q >> 2) * 64 + w * 4 + (q & 3);
        ws[e] = Wih2[row * HDIM + k];
    } else if (e < OFF_B1) {                 // pk_hh2
        int r = e - OFF_HH2;  int k = r >> 8, w = (r >> 4) & 15, q = r & 15;
        int row = (q >> 2) * 64 + w * 4 + (q & 3);
        ws[e] = Whh2[row * HDIM + k];
    } else if (e < OFF_B2) {                 // bias1 = b_ih1 + b_hh1
        int r = e - OFF_B1;   int w = r >> 4, q = r & 15;
        int row = (q >> 2) * 64 + w * 4 + (q & 3);
        ws[e] = bih1[row] + bhh1[row];
    } else {                                 // bias2
        int r = e - OFF_B2;   int w = r >> 4, q = r & 15;
        int row = (q >> 2) * 64 + w * 4 + (q & 3);
        ws[e] = bih2[row] + bhh2[row];
    }
}

// ---------------- main sequential LSTM ----------------
__global__ __launch_bounds__(1024) void lstm_main(
    const float* __restrict__ x,
    const float* __restrict__ ws,
    const float* __restrict__ Wout,
    const float* __restrict__ bout,
    float* __restrict__ out)
{
    const int tid  = threadIdx.x;
    const int lane = tid & 63;
    const int w    = __builtin_amdgcn_readfirstlane(tid >> 6);   // 0..15, wave-uniform
    const int b    = blockIdx.x * 64 + lane;

    const float* pk_ih1 = ws + OFF_IH1;
    const float* pk_hh1 = ws + OFF_HH1;
    const float* pk_ih2 = ws + OFF_IH2;
    const float* pk_hh2 = ws + OFF_HH2;

    __shared__ float h1s[HDIM][64];
    __shared__ float h2s[HDIM][64];

    for (int i = tid; i < HDIM * 64; i += 1024) {
        (&h1s[0][0])[i] = 0.0f;
        (&h2s[0][0])[i] = 0.0f;
    }

    float c1[4] = {0.f, 0.f, 0.f, 0.f};
    float c2[4] = {0.f, 0.f, 0.f, 0.f};

    const v16f bs1 = *(const v16f*)(ws + OFF_B1 + w * 16);
    const v16f bs2 = *(const v16f*)(ws + OFF_B2 + w * 16);

    const float* xp = x + (long)b * (T_STEPS * IN_DIM);

    __syncthreads();

    for (int t = 0; t < T_STEPS; ++t) {
        // ---- x_t
        float xv[IN_DIM];
        #pragma unroll
        for (int k = 0; k < IN_DIM; ++k) xv[k] = xp[t * IN_DIM + k];

        // ---- layer-1 gates: acc[q], q = g*4+jj
        float acc[16];
        #pragma unroll
        for (int q = 0; q < 16; ++q) acc[q] = bs1[q];

        #pragma unroll
        for (int k = 0; k < IN_DIM; ++k) {
            v16f wv = *(const v16f*)(pk_ih1 + (k * 16 + w) * 16);
            #pragma unroll
            for (int q = 0; q < 16; ++q) acc[q] = __builtin_fmaf(wv[q], xv[k], acc[q]);
        }
        #pragma unroll 4
        for (int k = 0; k < HDIM; ++k) {
            float hk = h1s[k][lane];
            v16f wv = *(const v16f*)(pk_hh1 + (k * 16 + w) * 16);
            #pragma unroll
            for (int q = 0; q < 16; ++q) acc[q] = __builtin_fmaf(wv[q], hk, acc[q]);
        }
        __syncthreads();                       // B1: everyone done reading old h1s

        #pragma unroll
        for (int jj = 0; jj < 4; ++jj) {
            float ig = fast_sig (acc[jj]);
            float fg = fast_sig (acc[4 + jj]);
            float gg = fast_tanh(acc[8 + jj]);
            float og = fast_sig (acc[12 + jj]);
            float c  = fg * c1[jj] + ig * gg;
            c1[jj]   = c;
            h1s[w * 4 + jj][lane] = og * fast_tanh(c);
        }
        __syncthreads();                       // B2: new h1s visible

        // ---- layer-2 gates
        #pragma unroll
        for (int q = 0; q < 16; ++q) acc[q] = bs2[q];

        #pragma unroll 4
        for (int k = 0; k < HDIM; ++k) {
            float h1k = h1s[k][lane];
            v16f wv = *(const v16f*)(pk_ih2 + (k * 16 + w) * 16);
            #pragma unroll
            for (int q = 0; q < 16; ++q) acc[q] = __builtin_fmaf(wv[q], h1k, acc[q]);
        }
        #pragma unroll 4
        for (int k = 0; k < HDIM; ++k) {
            float h2k = h2s[k][lane];
            v16f wv = *(const v16f*)(pk_hh2 + (k * 16 + w) * 16);
            #pragma unroll
            for (int q = 0; q < 16; ++q) acc[q] = __builtin_fmaf(wv[q], h2k, acc[q]);
        }
        __syncthreads();                       // B3: everyone done reading old h2s

        #pragma unroll
        for (int jj = 0; jj < 4; ++jj) {
            float ig = fast_sig (acc[jj]);
            float fg = fast_sig (acc[4 + jj]);
            float gg = fast_tanh(acc[8 + jj]);
            float og = fast_sig (acc[12 + jj]);
            float c  = fg * c2[jj] + ig * gg;
            c2[jj]   = c;
            h2s[w * 4 + jj][lane] = og * fast_tanh(c);
        }
        __syncthreads();                       // B4: new h2s visible
    }

    // ---- output head: out[b][0][o] = sum_j Wout[o][j] * h2[j] + bout[o]
    if (w == 0) {
        float o0 = bout[0], o1 = bout[1], o2 = bout[2];
        #pragma unroll 8
        for (int j = 0; j < HDIM; ++j) {
            float h = h2s[j][lane];
            o0 = __builtin_fmaf(Wout[j],        h, o0);
            o1 = __builtin_fmaf(Wout[64 + j],   h, o1);
            o2 = __builtin_fmaf(Wout[128 + j],  h, o2);
        }
        out[b * 3 + 0] = o0;
        out[b * 3 + 1] = o1;
        out[b * 3 + 2] = o2;
    }
}

extern "C" void kernel_launch(void* const* d_in, const int* in_sizes, int n_in,
                              void* d_out, int out_size, void* d_ws, size_t ws_size,
                              hipStream_t stream) {
    const float* x     = (const float*)d_in[0];
    const float* Wih1  = (const float*)d_in[1];
    const float* Whh1  = (const float*)d_in[2];
    const float* bih1  = (const float*)d_in[3];
    const float* bhh1  = (const float*)d_in[4];
    const float* Wih2  = (const float*)d_in[5];
    const float* Whh2  = (const float*)d_in[6];
    const float* bih2  = (const float*)d_in[7];
    const float* bhh2  = (const float*)d_in[8];
    const float* Wout  = (const float*)d_in[9];
    const float* bout  = (const float*)d_in[10];
    float* ws  = (float*)d_ws;
    float* out = (float*)d_out;

    pack_kernel<<<(WS_FLOATS + 255) / 256, 256, 0, stream>>>(
        Wih1, Whh1, bih1, bhh1, Wih2, Whh2, bih2, bhh2, ws);

    lstm_main<<<B_TOT / 64, 1024, 0, stream>>>(x, ws, Wout, bout, out);
}

// Round 2
// 672.972 us; speedup vs baseline: 6.2729x; 6.2729x over previous
//
#include <hip/hip_runtime.h>
#include <hip/hip_bf16.h>

// LSTM: B=16384, T=200, IN=9, H=64, OUT=3, 2 layers + linear head.
// Round 2: f16 MFMA restructure.
//   Block = 16 batches, 256 threads (4 waves). Grid = 1024 blocks.
//   Per step, per layer: GEMM [16 batch x K] @ [K x 256 gates] via
//   v_mfma_f32_16x16x32_f16. Wave w owns gate n-tiles {w, w+4, w+8, w+12}
//   => each lane holds i,f,g,o for (4 batches x 1 cell) in C fragments.
//   Weights pre-packed into B-fragment layout, register-resident (112 VGPR).
//   h1/h2 as f16 in LDS [16][72] (pad => 2-way banks, free).
//   x staged in 8-step LDS windows, A-fragment read as ds_read_b64.
// Fragment layouts (gfx950 16x16x32):
//   A: lane l holds A[m=l&15][k=4*(l>>4)+(j&3)+16*(j>>2)], j=0..7
//   B: lane l holds B[k=4*(l>>4)+(j&3)+16*(j>>2)][n=l&15]
//   C/D: col=l&15, row=(l>>4)*4+reg   (m89-verified)

#define B_TOT   16384
#define T_STEPS 200
#define IN_DIM  9
#define HDIM    64

// ws layout in _Float16 units
#define PK1_OFF 0         // [3][16][64][8] = 24576 f16
#define PK2_OFF 24576     // [4][16][64][8] = 32768 f16
#define BSUM_HALF_OFF 57344   // then 512 f32 (b1[256], b2[256])
#define PACK_W_TOT 57344
#define PACK_TOT (PACK_W_TOT + 512)

typedef _Float16 half8 __attribute__((ext_vector_type(8)));
typedef _Float16 half4 __attribute__((ext_vector_type(4)));
typedef float    f32x4 __attribute__((ext_vector_type(4)));

__device__ __forceinline__ float fast_sig(float x) {
    return __builtin_amdgcn_rcpf(1.0f + __expf(-x));
}
__device__ __forceinline__ float fast_tanh(float x) {
    return 1.0f - 2.0f * __builtin_amdgcn_rcpf(1.0f + __expf(2.0f * x));
}

// ---------------- prep: repack weights into B-fragment layout ----------------
__global__ void pack_kernel(const float* __restrict__ Wih1, const float* __restrict__ Whh1,
                            const float* __restrict__ bih1, const float* __restrict__ bhh1,
                            const float* __restrict__ Wih2, const float* __restrict__ Whh2,
                            const float* __restrict__ bih2, const float* __restrict__ bhh2,
                            float* __restrict__ ws) {
    int e = blockIdx.x * 256 + threadIdx.x;
    if (e >= PACK_TOT) return;
    _Float16* wh = (_Float16*)ws;
    float* bptr = (float*)(wh + BSUM_HALF_OFF);
    if (e < PK2_OFF) {
        // layer1 aug weights: k<64 -> W_hh1[q][k]; 64<=k<73 -> W_ih1[q][k-64]; else 0
        int j = e & 7, lane = (e >> 3) & 63, nt = (e >> 9) & 15, c = e >> 13;
        int k = c * 32 + 4 * (lane >> 4) + (j & 3) + 16 * (j >> 2);
        int q = nt * 16 + (lane & 15);
        float v = 0.0f;
        if (k < 64)      v = Whh1[q * 64 + k];
        else if (k < 73) v = Wih1[q * 9 + (k - 64)];
        wh[e] = (_Float16)v;
    } else if (e < PACK_W_TOT) {
        // layer2 aug weights: A2=[h1(new) 0..63, h2(old) 64..127]
        int e2 = e - PK2_OFF;
        int j = e2 & 7, lane = (e2 >> 3) & 63, nt = (e2 >> 9) & 15, c = e2 >> 13;
        int k = c * 32 + 4 * (lane >> 4) + (j & 3) + 16 * (j >> 2);
        int q = nt * 16 + (lane & 15);
        float v = (k < 64) ? Wih2[q * 64 + k] : Whh2[q * 64 + (k - 64)];
        wh[e] = (_Float16)v;
    } else if (e < PACK_W_TOT + 256) {
        int q = e - PACK_W_TOT;
        bptr[q] = bih1[q] + bhh1[q];
    } else {
        int q = e - PACK_W_TOT - 256;
        bptr[256 + q] = bih2[q] + bhh2[q];
    }
}

// ---------------- main sequential LSTM (MFMA) ----------------
__global__ __launch_bounds__(256, 2) void lstm_mfma(
    const float* __restrict__ x,
    const float* __restrict__ ws_f,
    const float* __restrict__ Wout,
    const float* __restrict__ bout,
    float* __restrict__ out)
{
    const int tid  = threadIdx.x;
    const int lane = tid & 63;
    const int w    = __builtin_amdgcn_readfirstlane(tid >> 6);   // 0..3
    const int l15  = lane & 15;
    const int l4   = lane >> 4;

    const _Float16* wh  = (const _Float16*)ws_f;
    const _Float16* pk1 = wh + PK1_OFF;
    const _Float16* pk2 = wh + PK2_OFF;
    const float* bsum   = (const float*)(wh + BSUM_HALF_OFF);

    __shared__ _Float16 h1s[16][72];
    __shared__ _Float16 h2s[16][72];
    __shared__ _Float16 xwin[8][16][12];   // [step&7][batch][k, 9 real + 3 zero-pad]

    for (int i = tid; i < 16 * 72; i += 256) {
        (&h1s[0][0])[i] = (_Float16)0.0f;
        (&h2s[0][0])[i] = (_Float16)0.0f;
    }
    for (int i = tid; i < 8 * 16 * 12; i += 256) (&xwin[0][0][0])[i] = (_Float16)0.0f;
    __syncthreads();   // zeros (incl. x pads) committed before window writes

    const int bbase = blockIdx.x * 16;

    // cooperative 8-step x window load: 16 batches x 72 floats
    auto load_window = [&](int wbase) {
        const int b  = tid >> 4;       // 0..15
        const int e0 = tid & 15;
        const float* xb = x + (long)(bbase + b) * (T_STEPS * IN_DIM) + wbase * IN_DIM;
        #pragma unroll
        for (int r = 0; r < 5; ++r) {
            int idx = e0 + 16 * r;
            if (idx < 72) {
                int s = idx / 9, k = idx - s * 9;
                xwin[s][b][k] = (_Float16)xb[idx];
            }
        }
    };
    load_window(0);

    // register-resident B fragments (weights)
    half8 bw1[3][4], bw2[4][4];
    #pragma unroll
    for (int c = 0; c < 3; ++c)
        #pragma unroll
        for (int g = 0; g < 4; ++g)
            bw1[c][g] = *(const half8*)(pk1 + (((c * 16) + (w + 4 * g)) * 64 + lane) * 8);
    #pragma unroll
    for (int c = 0; c < 4; ++c)
        #pragma unroll
        for (int g = 0; g < 4; ++g)
            bw2[c][g] = *(const half8*)(pk2 + (((c * 16) + (w + 4 * g)) * 64 + lane) * 8);

    float bias1[4], bias2[4];
    #pragma unroll
    for (int g = 0; g < 4; ++g) {
        bias1[g] = bsum[(w + 4 * g) * 16 + l15];
        bias2[g] = bsum[256 + (w + 4 * g) * 16 + l15];
    }

    f32x4 c1 = {0.f, 0.f, 0.f, 0.f};
    f32x4 c2 = {0.f, 0.f, 0.f, 0.f};

    __syncthreads();   // window 0 visible

    for (int t = 0; t < T_STEPS; ++t) {
        const int ts = t & 7;

        // ---- phase a: read all A-frags that depend on OLD state
        half8 a1[3];    // layer1: chunks 0,1 = h1(old->becomes new at t>0 semantics: h1s holds h1_{t-1}), chunk2 = x_t
        half8 a2h[2];   // layer2 chunks 2,3 operand = h2_{t-1}
        {
            const _Float16* r1 = &h1s[l15][4 * l4];
            const _Float16* r2 = &h2s[l15][4 * l4];
            #pragma unroll
            for (int c = 0; c < 2; ++c) {
                half4 lo  = *(const half4*)(r1 + c * 32);
                half4 hi  = *(const half4*)(r1 + c * 32 + 16);
                a1[c]  = __builtin_shufflevector(lo, hi, 0, 1, 2, 3, 4, 5, 6, 7);
                half4 lo2 = *(const half4*)(r2 + c * 32);
                half4 hi2 = *(const half4*)(r2 + c * 32 + 16);
                a2h[c] = __builtin_shufflevector(lo2, hi2, 0, 1, 2, 3, 4, 5, 6, 7);
            }
            half4 z = {(_Float16)0.f, (_Float16)0.f, (_Float16)0.f, (_Float16)0.f};
            half4 xl = z;
            if (l4 < 3) xl = *(const half4*)&xwin[ts][l15][4 * l4];
            a1[2] = __builtin_shufflevector(xl, z, 0, 1, 2, 3, 4, 5, 6, 7);
        }
        __syncthreads();   // B1: all reads of h1s/h2s/xwin done

        // refill x window (writes xwin; all reads of old window complete)
        if (ts == 7 && t + 1 < T_STEPS) load_window(t + 1);

        // ---- layer1 MFMA: gates1 = [h1, x] @ W1aug + b1
        f32x4 C[4];
        #pragma unroll
        for (int g = 0; g < 4; ++g) C[g] = (f32x4){bias1[g], bias1[g], bias1[g], bias1[g]};
        #pragma unroll
        for (int g = 0; g < 4; ++g) {
            C[g] = __builtin_amdgcn_mfma_f32_16x16x32_f16(a1[0], bw1[0][g], C[g], 0, 0, 0);
            C[g] = __builtin_amdgcn_mfma_f32_16x16x32_f16(a1[1], bw1[1][g], C[g], 0, 0, 0);
            C[g] = __builtin_amdgcn_mfma_f32_16x16x32_f16(a1[2], bw1[2][g], C[g], 0, 0, 0);
        }

        // ---- layer1 cell update: lane = (4 batches: 4*l4+r) x (cell j = w*16+l15)
        _Float16 h1n[4];
        #pragma unroll
        for (int r = 0; r < 4; ++r) {
            float ig = fast_sig (C[0][r]);
            float fg = fast_sig (C[1][r]);
            float gg = fast_tanh(C[2][r]);
            float og = fast_sig (C[3][r]);
            float cc = fg * c1[r] + ig * gg;
            c1[r] = cc;
            h1n[r] = (_Float16)(og * fast_tanh(cc));
        }
        #pragma unroll
        for (int r = 0; r < 4; ++r) h1s[4 * l4 + r][w * 16 + l15] = h1n[r];
        __syncthreads();   // B2: h1_new visible

        // ---- read h1_new A-frags (layer2 chunks 0,1)
        half8 a2[2];
        {
            const _Float16* r1 = &h1s[l15][4 * l4];
            #pragma unroll
            for (int c = 0; c < 2; ++c) {
                half4 lo = *(const half4*)(r1 + c * 32);
                half4 hi = *(const half4*)(r1 + c * 32 + 16);
                a2[c] = __builtin_shufflevector(lo, hi, 0, 1, 2, 3, 4, 5, 6, 7);
            }
        }

        // ---- layer2 MFMA: gates2 = [h1_new, h2_old] @ W2aug + b2
        f32x4 D[4];
        #pragma unroll
        for (int g = 0; g < 4; ++g) D[g] = (f32x4){bias2[g], bias2[g], bias2[g], bias2[g]};
        #pragma unroll
        for (int g = 0; g < 4; ++g) {
            D[g] = __builtin_amdgcn_mfma_f32_16x16x32_f16(a2[0],  bw2[0][g], D[g], 0, 0, 0);
            D[g] = __builtin_amdgcn_mfma_f32_16x16x32_f16(a2[1],  bw2[1][g], D[g], 0, 0, 0);
            D[g] = __builtin_amdgcn_mfma_f32_16x16x32_f16(a2h[0], bw2[2][g], D[g], 0, 0, 0);
            D[g] = __builtin_amdgcn_mfma_f32_16x16x32_f16(a2h[1], bw2[3][g], D[g], 0, 0, 0);
        }

        // ---- layer2 cell update
        _Float16 h2n[4];
        #pragma unroll
        for (int r = 0; r < 4; ++r) {
            float ig = fast_sig (D[0][r]);
            float fg = fast_sig (D[1][r]);
            float gg = fast_tanh(D[2][r]);
            float og = fast_sig (D[3][r]);
            float cc = fg * c2[r] + ig * gg;
            c2[r] = cc;
            h2n[r] = (_Float16)(og * fast_tanh(cc));
        }
        #pragma unroll
        for (int r = 0; r < 4; ++r) h2s[4 * l4 + r][w * 16 + l15] = h2n[r];
        __syncthreads();   // B3: h2_new visible (next step phase-a reads it)
    }

    // ---- output head: out[b][o] = Wout[o] . h2[b] + bout[o]
    if (tid < 48) {
        int bl = tid / 3, o = tid - bl * 3;
        float acc = bout[o];
        #pragma unroll 8
        for (int j = 0; j < HDIM; ++j)
            acc = __builtin_fmaf(Wout[o * 64 + j], (float)h2s[bl][j], acc);
        out[(bbase + bl) * 3 + o] = acc;
    }
}

extern "C" void kernel_launch(void* const* d_in, const int* in_sizes, int n_in,
                              void* d_out, int out_size, void* d_ws, size_t ws_size,
                              hipStream_t stream) {
    const float* x     = (const float*)d_in[0];
    const float* Wih1  = (const float*)d_in[1];
    const float* Whh1  = (const float*)d_in[2];
    const float* bih1  = (const float*)d_in[3];
    const float* bhh1  = (const float*)d_in[4];
    const float* Wih2  = (const float*)d_in[5];
    const float* Whh2  = (const float*)d_in[6];
    const float* bih2  = (const float*)d_in[7];
    const float* bhh2  = (const float*)d_in[8];
    const float* Wout  = (const float*)d_in[9];
    const float* bout  = (const float*)d_in[10];
    float* ws  = (float*)d_ws;
    float* out = (float*)d_out;

    pack_kernel<<<(PACK_TOT + 255) / 256, 256, 0, stream>>>(
        Wih1, Whh1, bih1, bhh1, Wih2, Whh2, bih2, bhh2, ws);

    lstm_mfma<<<B_TOT / 16, 256, 0, stream>>>(x, ws, Wout, bout, out);
}

// Round 3
// 656.361 us; speedup vs baseline: 6.4316x; 1.0253x over previous
//
#include <hip/hip_runtime.h>
#include <hip/hip_bf16.h>

// LSTM: B=16384, T=200, IN=9, H=64, OUT=3, 2 layers + linear head.
// Round 3: register-resident weights (pinned), perm-layout LDS (b128 frags),
//          2 barriers/step via double-buffered h state, early L2-partial MFMA.
// Block = 16 batches, 256 threads (4 waves). Grid = 1024 blocks.
// Wave w owns gate n-tiles {w, w+4, w+8, w+12}.
// Fragment layouts (gfx950 16x16x32):
//   A: lane l holds A[m=l&15][k=4*(l>>4)+(j&3)+16*(j>>2)], j=0..7
//   B: lane l holds B[k=4*(l>>4)+(j&3)+16*(j>>2)][n=l&15]
//   C/D: col=l&15, row=(l>>4)*4+reg
// LDS h-state is stored k-PERMUTED: k=c*32+4q+s      -> pos=c*32+8q+s
//                                   k=c*32+16+4q+s   -> pos=c*32+8q+4+s
// so an A-fragment chunk is 16 contiguous bytes: ds_read_b128 at [m][c*32+8*l4].

#define B_TOT   16384
#define T_STEPS 200
#define IN_DIM  9
#define HDIM    64

// ws layout in _Float16 units (same packing as R2, proven)
#define PK1_OFF 0         // [3][16][64][8] = 24576 f16
#define PK2_OFF 24576     // [4][16][64][8] = 32768 f16
#define BSUM_HALF_OFF 57344   // then 512 f32 (b1[256], b2[256])
#define PACK_W_TOT 57344
#define PACK_TOT (PACK_W_TOT + 512)

typedef _Float16 half8 __attribute__((ext_vector_type(8)));
typedef float    f32x4 __attribute__((ext_vector_type(4)));

__device__ __forceinline__ float fast_sig(float x) {
    return __builtin_amdgcn_rcpf(1.0f + __expf(-x));   // self-saturating
}
__device__ __forceinline__ float fast_tanh(float x) {
    return 1.0f - 2.0f * __builtin_amdgcn_rcpf(1.0f + __expf(2.0f * x));
}

// ---------------- prep: repack weights into B-fragment layout ----------------
__global__ void pack_kernel(const float* __restrict__ Wih1, const float* __restrict__ Whh1,
                            const float* __restrict__ bih1, const float* __restrict__ bhh1,
                            const float* __restrict__ Wih2, const float* __restrict__ Whh2,
                            const float* __restrict__ bih2, const float* __restrict__ bhh2,
                            float* __restrict__ ws) {
    int e = blockIdx.x * 256 + threadIdx.x;
    if (e >= PACK_TOT) return;
    _Float16* wh = (_Float16*)ws;
    float* bptr = (float*)(wh + BSUM_HALF_OFF);
    if (e < PK2_OFF) {
        int j = e & 7, lane = (e >> 3) & 63, nt = (e >> 9) & 15, c = e >> 13;
        int k = c * 32 + 4 * (lane >> 4) + (j & 3) + 16 * (j >> 2);
        int q = nt * 16 + (lane & 15);
        float v = 0.0f;
        if (k < 64)      v = Whh1[q * 64 + k];
        else if (k < 73) v = Wih1[q * 9 + (k - 64)];
        wh[e] = (_Float16)v;
    } else if (e < PACK_W_TOT) {
        int e2 = e - PK2_OFF;
        int j = e2 & 7, lane = (e2 >> 3) & 63, nt = (e2 >> 9) & 15, c = e2 >> 13;
        int k = c * 32 + 4 * (lane >> 4) + (j & 3) + 16 * (j >> 2);
        int q = nt * 16 + (lane & 15);
        float v = (k < 64) ? Wih2[q * 64 + k] : Whh2[q * 64 + (k - 64)];
        wh[e] = (_Float16)v;
    } else if (e < PACK_W_TOT + 256) {
        int q = e - PACK_W_TOT;
        bptr[q] = bih1[q] + bhh1[q];
    } else {
        int q = e - PACK_W_TOT - 256;
        bptr[256 + q] = bih2[q] + bhh2[q];
    }
}

// ---------------- main sequential LSTM (MFMA) ----------------
__global__ __launch_bounds__(256, 1) void lstm_mfma(
    const float* __restrict__ x,
    const float* __restrict__ ws_f,
    const float* __restrict__ Wout,
    const float* __restrict__ bout,
    float* __restrict__ out)
{
    const int tid  = threadIdx.x;
    const int lane = tid & 63;
    const int w    = __builtin_amdgcn_readfirstlane(tid >> 6);   // 0..3
    const int l15  = lane & 15;
    const int l4   = lane >> 4;

    const _Float16* wh  = (const _Float16*)ws_f;
    const _Float16* pk1 = wh + PK1_OFF;
    const _Float16* pk2 = wh + PK2_OFF;
    const float* bsum   = (const float*)(wh + BSUM_HALF_OFF);

    // perm-layout, double-buffered h state; pitch 72 halves = 144B (16B-aligned rows)
    __shared__ _Float16 h1s[2][16][72];
    __shared__ _Float16 h2s[2][16][72];
    __shared__ _Float16 xwin[8][16][40];   // pos 0..31 read by b128 (real x at perm pos of k=0..8)

    for (int i = tid; i < 2 * 16 * 72; i += 256) {
        (&h1s[0][0][0])[i] = (_Float16)0.0f;
        (&h1s[1][0][0])[i] = (_Float16)0.0f;   // NOTE: h1s[2]... flat covers both via loop below
    }
    // (re-zero cleanly: flatten both arrays fully)
    for (int i = tid; i < 2 * 16 * 72; i += 256) {
        (&h2s[0][0][0])[i] = (_Float16)0.0f;
    }
    for (int i = tid; i < 8 * 16 * 40; i += 256) (&xwin[0][0][0])[i] = (_Float16)0.0f;

    const int bbase = blockIdx.x * 16;

    // per-thread window-loader constants: thread handles batch tid>>4, elems e0+16r
    const int wb = tid >> 4;       // 0..15
    const int e0 = tid & 15;
    int lw_s[5], lw_pos[5], lw_idx[5], lw_ok[5];
    #pragma unroll
    for (int r = 0; r < 5; ++r) {
        int idx = e0 + 16 * r;
        lw_ok[r]  = (idx < 72);
        int s = idx / 9, k = idx - s * 9;
        lw_s[r]   = s;
        lw_idx[r] = idx;
        lw_pos[r] = 8 * (k >> 2) + (k & 3);   // perm position of k within chunk
    }
    const float* xb = x + (long)(bbase + wb) * (T_STEPS * IN_DIM);

    auto load_window = [&](int wbase) {
        float v[5];
        #pragma unroll
        for (int r = 0; r < 5; ++r)
            if (lw_ok[r]) v[r] = xb[wbase * IN_DIM + lw_idx[r]];
        #pragma unroll
        for (int r = 0; r < 5; ++r)
            if (lw_ok[r]) xwin[lw_s[r]][wb][lw_pos[r]] = (_Float16)v[r];
    };
    __syncthreads();               // zeros committed before window writes
    load_window(0);

    // ---- register-resident B fragments (weights): 28 x half8 = 112 VGPR
    half8 bw1[3][4], bw2[4][4];
    #pragma unroll
    for (int c = 0; c < 3; ++c)
        #pragma unroll
        for (int g = 0; g < 4; ++g)
            bw1[c][g] = *(const half8*)(pk1 + (((c * 16) + (w + 4 * g)) * 64 + lane) * 8);
    #pragma unroll
    for (int c = 0; c < 4; ++c)
        #pragma unroll
        for (int g = 0; g < 4; ++g)
            bw2[c][g] = *(const half8*)(pk2 + (((c * 16) + (w + 4 * g)) * 64 + lane) * 8);
    // pin them: forbid rematerialization-by-reload inside the loop
    #pragma unroll
    for (int c = 0; c < 3; ++c)
        #pragma unroll
        for (int g = 0; g < 4; ++g)
            asm volatile("" : "+v"(bw1[c][g]));
    #pragma unroll
    for (int c = 0; c < 4; ++c)
        #pragma unroll
        for (int g = 0; g < 4; ++g)
            asm volatile("" : "+v"(bw2[c][g]));

    float bias1[4], bias2[4];
    #pragma unroll
    for (int g = 0; g < 4; ++g) {
        bias1[g] = bsum[(w + 4 * g) * 16 + l15];
        bias2[g] = bsum[256 + (w + 4 * g) * 16 + l15];
    }

    // h-write perm position for this thread's cell column j = w*16 + l15
    const int hpos = ((w >> 1) << 5) + 8 * (l15 >> 2) + (l15 & 3) + ((w & 1) << 2);

    f32x4 c1 = {0.f, 0.f, 0.f, 0.f};
    f32x4 c2 = {0.f, 0.f, 0.f, 0.f};

    __syncthreads();               // window 0 + zero h state visible

    int p = 0;
    for (int t = 0; t < T_STEPS; ++t) {
        const int ts = t & 7;

        // ---- phase a: all old-state A-fragments as single b128 reads
        half8 a1c0 = *(const half8*)&h1s[p][l15][ 0 + 8 * l4];
        half8 a1c1 = *(const half8*)&h1s[p][l15][32 + 8 * l4];
        half8 a2h0 = *(const half8*)&h2s[p][l15][ 0 + 8 * l4];
        half8 a2h1 = *(const half8*)&h2s[p][l15][32 + 8 * l4];
        half8 ax   = *(const half8*)&xwin[ts][l15][8 * l4];

        // ---- layer1 MFMA: gates1 = [h1_old | x] @ W1aug + b1
        f32x4 C[4];
        #pragma unroll
        for (int g = 0; g < 4; ++g) C[g] = (f32x4){bias1[g], bias1[g], bias1[g], bias1[g]};
        #pragma unroll
        for (int g = 0; g < 4; ++g) {
            C[g] = __builtin_amdgcn_mfma_f32_16x16x32_f16(a1c0, bw1[0][g], C[g], 0, 0, 0);
            C[g] = __builtin_amdgcn_mfma_f32_16x16x32_f16(a1c1, bw1[1][g], C[g], 0, 0, 0);
            C[g] = __builtin_amdgcn_mfma_f32_16x16x32_f16(ax,   bw1[2][g], C[g], 0, 0, 0);
        }

        // ---- layer2 partial MFMA on h2_old (independent of layer1 result)
        f32x4 D[4];
        #pragma unroll
        for (int g = 0; g < 4; ++g) D[g] = (f32x4){bias2[g], bias2[g], bias2[g], bias2[g]};
        #pragma unroll
        for (int g = 0; g < 4; ++g) {
            D[g] = __builtin_amdgcn_mfma_f32_16x16x32_f16(a2h0, bw2[2][g], D[g], 0, 0, 0);
            D[g] = __builtin_amdgcn_mfma_f32_16x16x32_f16(a2h1, bw2[3][g], D[g], 0, 0, 0);
        }

        // ---- layer1 cell update (lane: batches 4*l4+r, cell w*16+l15)
        #pragma unroll
        for (int r = 0; r < 4; ++r) {
            float ig = fast_sig (C[0][r]);
            float fg = fast_sig (C[1][r]);
            float gg = fast_tanh(C[2][r]);
            float og = fast_sig (C[3][r]);
            float cc = fg * c1[r] + ig * gg;
            c1[r] = cc;
            h1s[1 - p][4 * l4 + r][hpos] = (_Float16)(og * fast_tanh(cc));
        }
        __syncthreads();           // B_a: h1_new visible (old-state reads all done pre-write)

        // refill x window (old window fully consumed pre-B_a; visible after B_b)
        if (ts == 7 && t + 1 < T_STEPS) load_window(t + 1);

        // ---- finish layer2: h1_new chunks
        half8 a20 = *(const half8*)&h1s[1 - p][l15][ 0 + 8 * l4];
        half8 a21 = *(const half8*)&h1s[1 - p][l15][32 + 8 * l4];
        #pragma unroll
        for (int g = 0; g < 4; ++g) {
            D[g] = __builtin_amdgcn_mfma_f32_16x16x32_f16(a20, bw2[0][g], D[g], 0, 0, 0);
            D[g] = __builtin_amdgcn_mfma_f32_16x16x32_f16(a21, bw2[1][g], D[g], 0, 0, 0);
        }

        // ---- layer2 cell update
        #pragma unroll
        for (int r = 0; r < 4; ++r) {
            float ig = fast_sig (D[0][r]);
            float fg = fast_sig (D[1][r]);
            float gg = fast_tanh(D[2][r]);
            float og = fast_sig (D[3][r]);
            float cc = fg * c2[r] + ig * gg;
            c2[r] = cc;
            h2s[1 - p][4 * l4 + r][hpos] = (_Float16)(og * fast_tanh(cc));
        }
        __syncthreads();           // B_b: h2_new + refilled window visible
        p ^= 1;
    }

    // ---- output head: out[b][o] = Wout[o] . h2[b] + bout[o]  (h2s is perm-stored)
    if (tid < 48) {
        int bl = tid / 3, o = tid - bl * 3;
        float acc = bout[o];
        #pragma unroll 8
        for (int pos = 0; pos < HDIM; ++pos) {
            int sub = pos & 31;
            int j = (pos >> 5) * 32 + (((sub >> 2) & 1) << 4) + ((sub >> 3) << 2) + (sub & 3);
            acc = __builtin_fmaf(Wout[o * 64 + j], (float)h2s[p][bl][pos], acc);
        }
        out[(bbase + bl) * 3 + o] = acc;
    }
}

extern "C" void kernel_launch(void* const* d_in, const int* in_sizes, int n_in,
                              void* d_out, int out_size, void* d_ws, size_t ws_size,
                              hipStream_t stream) {
    const float* x     = (const float*)d_in[0];
    const float* Wih1  = (const float*)d_in[1];
    const float* Whh1  = (const float*)d_in[2];
    const float* bih1  = (const float*)d_in[3];
    const float* bhh1  = (const float*)d_in[4];
    const float* Wih2  = (const float*)d_in[5];
    const float* Whh2  = (const float*)d_in[6];
    const float* bih2  = (const float*)d_in[7];
    const float* bhh2  = (const float*)d_in[8];
    const float* Wout  = (const float*)d_in[9];
    const float* bout  = (const float*)d_in[10];
    float* ws  = (float*)d_ws;
    float* out = (float*)d_out;

    pack_kernel<<<(PACK_TOT + 255) / 256, 256, 0, stream>>>(
        Wih1, Whh1, bih1, bhh1, Wih2, Whh2, bih2, bhh2, ws);

    lstm_mfma<<<B_TOT / 16, 256, 0, stream>>>(x, ws, Wout, bout, out);
}

// Round 4
// 609.112 us; speedup vs baseline: 6.9305x; 1.0776x over previous
//
#include <hip/hip_runtime.h>
#include <hip/hip_bf16.h>

// LSTM: B=16384, T=200, IN=9, H=64, OUT=3, 2 layers + linear head.
// Round 4: TRUE register-resident weights via in-loop asm pin (R3's pre-loop
//          pin failed: VGPR stayed 108 => 28KB/wave/step L2 reload traffic).
//          Plus: fold log2e activation scales into packed weights/biases.
// Block = 16 batches, 256 threads (4 waves). Grid = 1024 blocks.
// Wave w owns gate n-tiles {w, w+4, w+8, w+12}.
// Fragment layouts (gfx950 16x16x32):
//   A: lane l holds A[m=l&15][k=4*(l>>4)+(j&3)+16*(j>>2)], j=0..7
//   B: lane l holds B[k=...][n=l&15]
//   C/D: col=l&15, row=(l>>4)*4+reg
// LDS h-state k-PERMUTED so an A-chunk is one ds_read_b128 (see R3).
// Weight pre-scaling: rows i,f,o x(-log2e); rows g x(+2*log2e); biases same.
//   sigma(x)  = rcp(1+exp2(y)),            y = -log2e*x
//   tanh(g)   = fma(-2, rcp(1+exp2(yg)),1), yg = 2*log2e*g
//   tanh(c)   = fma( 2, rcp(1+exp2(-2*log2e*c)), -1)   (runtime scale, c unscaled)

#define B_TOT   16384
#define T_STEPS 200
#define IN_DIM  9
#define HDIM    64

#define PK1_OFF 0         // [3][16][64][8] = 24576 f16
#define PK2_OFF 24576     // [4][16][64][8] = 32768 f16
#define BSUM_HALF_OFF 57344   // then 512 f32 (b1[256], b2[256])
#define PACK_W_TOT 57344
#define PACK_TOT (PACK_W_TOT + 512)

#define L2E      1.44269504089f
#define NEG2L2E -2.88539008178f

typedef _Float16 half8 __attribute__((ext_vector_type(8)));
typedef float    f32x4 __attribute__((ext_vector_type(4)));

__device__ __forceinline__ float sig_y(float y) {           // y pre-scaled
    return __builtin_amdgcn_rcpf(1.0f + __builtin_amdgcn_exp2f(y));
}

// ---------------- prep: repack weights (B-frag layout, act-scales folded) ----
__global__ void pack_kernel(const float* __restrict__ Wih1, const float* __restrict__ Whh1,
                            const float* __restrict__ bih1, const float* __restrict__ bhh1,
                            const float* __restrict__ Wih2, const float* __restrict__ Whh2,
                            const float* __restrict__ bih2, const float* __restrict__ bhh2,
                            float* __restrict__ ws) {
    int e = blockIdx.x * 256 + threadIdx.x;
    if (e >= PACK_TOT) return;
    _Float16* wh = (_Float16*)ws;
    float* bptr = (float*)(wh + BSUM_HALF_OFF);
    // gate scale by row q in [0,256): type = q>>6 (0=i,1=f,2=g,3=o)
    auto gscale = [](int q) -> float {
        int gt = q >> 6;
        return (gt == 2) ? (2.0f * L2E) : -L2E;
    };
    if (e < PK2_OFF) {
        int j = e & 7, lane = (e >> 3) & 63, nt = (e >> 9) & 15, c = e >> 13;
        int k = c * 32 + 4 * (lane >> 4) + (j & 3) + 16 * (j >> 2);
        int q = nt * 16 + (lane & 15);
        float v = 0.0f;
        if (k < 64)      v = Whh1[q * 64 + k];
        else if (k < 73) v = Wih1[q * 9 + (k - 64)];
        wh[e] = (_Float16)(v * gscale(q));
    } else if (e < PACK_W_TOT) {
        int e2 = e - PK2_OFF;
        int j = e2 & 7, lane = (e2 >> 3) & 63, nt = (e2 >> 9) & 15, c = e2 >> 13;
        int k = c * 32 + 4 * (lane >> 4) + (j & 3) + 16 * (j >> 2);
        int q = nt * 16 + (lane & 15);
        float v = (k < 64) ? Wih2[q * 64 + k] : Whh2[q * 64 + (k - 64)];
        wh[e] = (_Float16)(v * gscale(q));
    } else if (e < PACK_W_TOT + 256) {
        int q = e - PACK_W_TOT;
        bptr[q] = (bih1[q] + bhh1[q]) * gscale(q);
    } else {
        int q = e - PACK_W_TOT - 256;
        bptr[256 + q] = (bih2[q] + bhh2[q]) * gscale(q);
    }
}

// ---------------- main sequential LSTM (MFMA) ----------------
__global__ __launch_bounds__(256, 1) void lstm_mfma(
    const float* __restrict__ x,
    const float* __restrict__ ws_f,
    const float* __restrict__ Wout,
    const float* __restrict__ bout,
    float* __restrict__ out)
{
    const int tid  = threadIdx.x;
    const int lane = tid & 63;
    const int w    = __builtin_amdgcn_readfirstlane(tid >> 6);   // 0..3
    const int l15  = lane & 15;
    const int l4   = lane >> 4;

    const _Float16* wh  = (const _Float16*)ws_f;
    const _Float16* pk1 = wh + PK1_OFF;
    const _Float16* pk2 = wh + PK2_OFF;
    const float* bsum   = (const float*)(wh + BSUM_HALF_OFF);

    __shared__ _Float16 h1s[2][16][72];
    __shared__ _Float16 h2s[2][16][72];
    __shared__ _Float16 xwin[8][16][40];

    for (int i = tid; i < 2 * 16 * 72; i += 256) {
        (&h1s[0][0][0])[i] = (_Float16)0.0f;
        (&h2s[0][0][0])[i] = (_Float16)0.0f;
    }
    for (int i = tid; i < 8 * 16 * 40; i += 256) (&xwin[0][0][0])[i] = (_Float16)0.0f;

    const int bbase = blockIdx.x * 16;

    const int wb = tid >> 4;       // window loader: batch wb, elems e0+16r
    const int e0 = tid & 15;
    int lw_s[5], lw_pos[5], lw_idx[5], lw_ok[5];
    #pragma unroll
    for (int r = 0; r < 5; ++r) {
        int idx = e0 + 16 * r;
        lw_ok[r]  = (idx < 72);
        int s = idx / 9, k = idx - s * 9;
        lw_s[r]   = s;
        lw_idx[r] = idx;
        lw_pos[r] = 8 * (k >> 2) + (k & 3);
    }
    const float* xb = x + (long)(bbase + wb) * (T_STEPS * IN_DIM);

    auto load_window = [&](int wbase) {
        float v[5];
        #pragma unroll
        for (int r = 0; r < 5; ++r)
            if (lw_ok[r]) v[r] = xb[wbase * IN_DIM + lw_idx[r]];
        #pragma unroll
        for (int r = 0; r < 5; ++r)
            if (lw_ok[r]) xwin[lw_s[r]][wb][lw_pos[r]] = (_Float16)v[r];
    };
    __syncthreads();
    load_window(0);

    // ---- load B fragments (weights): 28 x half8 = 112 VGPR
    half8 bw1_00, bw1_01, bw1_02, bw1_03;
    half8 bw1_10, bw1_11, bw1_12, bw1_13;
    half8 bw1_20, bw1_21, bw1_22, bw1_23;
    half8 bw2_00, bw2_01, bw2_02, bw2_03;
    half8 bw2_10, bw2_11, bw2_12, bw2_13;
    half8 bw2_20, bw2_21, bw2_22, bw2_23;
    half8 bw2_30, bw2_31, bw2_32, bw2_33;
    {
        #define LD1(c,g) *(const half8*)(pk1 + (((c * 16) + (w + 4 * g)) * 64 + lane) * 8)
        #define LD2(c,g) *(const half8*)(pk2 + (((c * 16) + (w + 4 * g)) * 64 + lane) * 8)
        bw1_00 = LD1(0,0); bw1_01 = LD1(0,1); bw1_02 = LD1(0,2); bw1_03 = LD1(0,3);
        bw1_10 = LD1(1,0); bw1_11 = LD1(1,1); bw1_12 = LD1(1,2); bw1_13 = LD1(1,3);
        bw1_20 = LD1(2,0); bw1_21 = LD1(2,1); bw1_22 = LD1(2,2); bw1_23 = LD1(2,3);
        bw2_00 = LD2(0,0); bw2_01 = LD2(0,1); bw2_02 = LD2(0,2); bw2_03 = LD2(0,3);
        bw2_10 = LD2(1,0); bw2_11 = LD2(1,1); bw2_12 = LD2(1,2); bw2_13 = LD2(1,3);
        bw2_20 = LD2(2,0); bw2_21 = LD2(2,1); bw2_22 = LD2(2,2); bw2_23 = LD2(2,3);
        bw2_30 = LD2(3,0); bw2_31 = LD2(3,1); bw2_32 = LD2(3,2); bw2_33 = LD2(3,3);
        #undef LD1
        #undef LD2
    }

    float bias1[4], bias2[4];
    #pragma unroll
    for (int g = 0; g < 4; ++g) {
        bias1[g] = bsum[(w + 4 * g) * 16 + l15];
        bias2[g] = bsum[256 + (w + 4 * g) * 16 + l15];
    }

    const int hpos = ((w >> 1) << 5) + 8 * (l15 >> 2) + (l15 & 3) + ((w & 1) << 2);

    f32x4 c1 = {0.f, 0.f, 0.f, 0.f};
    f32x4 c2 = {0.f, 0.f, 0.f, 0.f};

    __syncthreads();

    int p = 0;
    for (int t = 0; t < T_STEPS; ++t) {
        const int ts = t & 7;

        // ---- IN-LOOP PIN: forces all 28 weight frags (+biases) loop-carried
        // in VGPRs; allocator cannot rematerialize them from memory.
        asm volatile("" :
            "+v"(bw1_00), "+v"(bw1_01), "+v"(bw1_02), "+v"(bw1_03),
            "+v"(bw1_10), "+v"(bw1_11), "+v"(bw1_12), "+v"(bw1_13),
            "+v"(bw1_20), "+v"(bw1_21), "+v"(bw1_22), "+v"(bw1_23));
        asm volatile("" :
            "+v"(bw2_00), "+v"(bw2_01), "+v"(bw2_02), "+v"(bw2_03),
            "+v"(bw2_10), "+v"(bw2_11), "+v"(bw2_12), "+v"(bw2_13),
            "+v"(bw2_20), "+v"(bw2_21), "+v"(bw2_22), "+v"(bw2_23),
            "+v"(bw2_30), "+v"(bw2_31), "+v"(bw2_32), "+v"(bw2_33),
            "+v"(bias1[0]), "+v"(bias1[1]), "+v"(bias1[2]), "+v"(bias1[3]),
            "+v"(bias2[0]), "+v"(bias2[1]), "+v"(bias2[2]), "+v"(bias2[3]));

        // ---- phase a: old-state A-fragments (single b128 reads)
        half8 a1c0 = *(const half8*)&h1s[p][l15][ 0 + 8 * l4];
        half8 a1c1 = *(const half8*)&h1s[p][l15][32 + 8 * l4];
        half8 a2h0 = *(const half8*)&h2s[p][l15][ 0 + 8 * l4];
        half8 a2h1 = *(const half8*)&h2s[p][l15][32 + 8 * l4];
        half8 ax   = *(const half8*)&xwin[ts][l15][8 * l4];

        // ---- layer1 MFMA
        f32x4 C[4];
        #pragma unroll
        for (int g = 0; g < 4; ++g) C[g] = (f32x4){bias1[g], bias1[g], bias1[g], bias1[g]};
        C[0] = __builtin_amdgcn_mfma_f32_16x16x32_f16(a1c0, bw1_00, C[0], 0, 0, 0);
        C[1] = __builtin_amdgcn_mfma_f32_16x16x32_f16(a1c0, bw1_01, C[1], 0, 0, 0);
        C[2] = __builtin_amdgcn_mfma_f32_16x16x32_f16(a1c0, bw1_02, C[2], 0, 0, 0);
        C[3] = __builtin_amdgcn_mfma_f32_16x16x32_f16(a1c0, bw1_03, C[3], 0, 0, 0);
        C[0] = __builtin_amdgcn_mfma_f32_16x16x32_f16(a1c1, bw1_10, C[0], 0, 0, 0);
        C[1] = __builtin_amdgcn_mfma_f32_16x16x32_f16(a1c1, bw1_11, C[1], 0, 0, 0);
        C[2] = __builtin_amdgcn_mfma_f32_16x16x32_f16(a1c1, bw1_12, C[2], 0, 0, 0);
        C[3] = __builtin_amdgcn_mfma_f32_16x16x32_f16(a1c1, bw1_13, C[3], 0, 0, 0);
        C[0] = __builtin_amdgcn_mfma_f32_16x16x32_f16(ax,   bw1_20, C[0], 0, 0, 0);
        C[1] = __builtin_amdgcn_mfma_f32_16x16x32_f16(ax,   bw1_21, C[1], 0, 0, 0);
        C[2] = __builtin_amdgcn_mfma_f32_16x16x32_f16(ax,   bw1_22, C[2], 0, 0, 0);
        C[3] = __builtin_amdgcn_mfma_f32_16x16x32_f16(ax,   bw1_23, C[3], 0, 0, 0);

        // ---- layer2 partial MFMA on h2_old (independent)
        f32x4 D[4];
        #pragma unroll
        for (int g = 0; g < 4; ++g) D[g] = (f32x4){bias2[g], bias2[g], bias2[g], bias2[g]};
        D[0] = __builtin_amdgcn_mfma_f32_16x16x32_f16(a2h0, bw2_20, D[0], 0, 0, 0);
        D[1] = __builtin_amdgcn_mfma_f32_16x16x32_f16(a2h0, bw2_21, D[1], 0, 0, 0);
        D[2] = __builtin_amdgcn_mfma_f32_16x16x32_f16(a2h0, bw2_22, D[2], 0, 0, 0);
        D[3] = __builtin_amdgcn_mfma_f32_16x16x32_f16(a2h0, bw2_23, D[3], 0, 0, 0);
        D[0] = __builtin_amdgcn_mfma_f32_16x16x32_f16(a2h1, bw2_30, D[0], 0, 0, 0);
        D[1] = __builtin_amdgcn_mfma_f32_16x16x32_f16(a2h1, bw2_31, D[1], 0, 0, 0);
        D[2] = __builtin_amdgcn_mfma_f32_16x16x32_f16(a2h1, bw2_32, D[2], 0, 0, 0);
        D[3] = __builtin_amdgcn_mfma_f32_16x16x32_f16(a2h1, bw2_33, D[3], 0, 0, 0);

        // ---- layer1 cell update (pre-scaled gates)
        #pragma unroll
        for (int r = 0; r < 4; ++r) {
            float ig = sig_y(C[0][r]);
            float fg = sig_y(C[1][r]);
            float gg = __builtin_fmaf(-2.0f, sig_y(C[2][r]), 1.0f);   // tanh(g)
            float og = sig_y(C[3][r]);
            float cc = __builtin_fmaf(fg, c1[r], ig * gg);
            c1[r] = cc;
            float th = __builtin_fmaf(2.0f, sig_y(cc * NEG2L2E), -1.0f);  // tanh(c)
            h1s[1 - p][4 * l4 + r][hpos] = (_Float16)(og * th);
        }
        __syncthreads();           // B_a: h1_new visible

        if (ts == 7 && t + 1 < T_STEPS) load_window(t + 1);

        // ---- finish layer2 with h1_new
        half8 a20 = *(const half8*)&h1s[1 - p][l15][ 0 + 8 * l4];
        half8 a21 = *(const half8*)&h1s[1 - p][l15][32 + 8 * l4];
        D[0] = __builtin_amdgcn_mfma_f32_16x16x32_f16(a20, bw2_00, D[0], 0, 0, 0);
        D[1] = __builtin_amdgcn_mfma_f32_16x16x32_f16(a20, bw2_01, D[1], 0, 0, 0);
        D[2] = __builtin_amdgcn_mfma_f32_16x16x32_f16(a20, bw2_02, D[2], 0, 0, 0);
        D[3] = __builtin_amdgcn_mfma_f32_16x16x32_f16(a20, bw2_03, D[3], 0, 0, 0);
        D[0] = __builtin_amdgcn_mfma_f32_16x16x32_f16(a21, bw2_10, D[0], 0, 0, 0);
        D[1] = __builtin_amdgcn_mfma_f32_16x16x32_f16(a21, bw2_11, D[1], 0, 0, 0);
        D[2] = __builtin_amdgcn_mfma_f32_16x16x32_f16(a21, bw2_12, D[2], 0, 0, 0);
        D[3] = __builtin_amdgcn_mfma_f32_16x16x32_f16(a21, bw2_13, D[3], 0, 0, 0);

        // ---- layer2 cell update
        #pragma unroll
        for (int r = 0; r < 4; ++r) {
            float ig = sig_y(D[0][r]);
            float fg = sig_y(D[1][r]);
            float gg = __builtin_fmaf(-2.0f, sig_y(D[2][r]), 1.0f);
            float og = sig_y(D[3][r]);
            float cc = __builtin_fmaf(fg, c2[r], ig * gg);
            c2[r] = cc;
            float th = __builtin_fmaf(2.0f, sig_y(cc * NEG2L2E), -1.0f);
            h2s[1 - p][4 * l4 + r][hpos] = (_Float16)(og * th);
        }
        __syncthreads();           // B_b: h2_new + window visible
        p ^= 1;
    }

    // ---- output head (h2s perm-stored)
    if (tid < 48) {
        int bl = tid / 3, o = tid - bl * 3;
        float acc = bout[o];
        #pragma unroll 8
        for (int pos = 0; pos < HDIM; ++pos) {
            int sub = pos & 31;
            int j = (pos >> 5) * 32 + (((sub >> 2) & 1) << 4) + ((sub >> 3) << 2) + (sub & 3);
            acc = __builtin_fmaf(Wout[o * 64 + j], (float)h2s[p][bl][pos], acc);
        }
        out[(bbase + bl) * 3 + o] = acc;
    }
}

extern "C" void kernel_launch(void* const* d_in, const int* in_sizes, int n_in,
                              void* d_out, int out_size, void* d_ws, size_t ws_size,
                              hipStream_t stream) {
    const float* x     = (const float*)d_in[0];
    const float* Wih1  = (const float*)d_in[1];
    const float* Whh1  = (const float*)d_in[2];
    const float* bih1  = (const float*)d_in[3];
    const float* bhh1  = (const float*)d_in[4];
    const float* Wih2  = (const float*)d_in[5];
    const float* Whh2  = (const float*)d_in[6];
    const float* bih2  = (const float*)d_in[7];
    const float* bhh2  = (const float*)d_in[8];
    const float* Wout  = (const float*)d_in[9];
    const float* bout  = (const float*)d_in[10];
    float* ws  = (float*)d_ws;
    float* out = (float*)d_out;

    pack_kernel<<<(PACK_TOT + 255) / 256, 256, 0, stream>>>(
        Wih1, Whh1, bih1, bhh1, Wih2, Whh2, bih2, bhh2, ws);

    lstm_mfma<<<B_TOT / 16, 256, 0, stream>>>(x, ws, Wout, bout, out);
}